// Round 1
// baseline (901.708 us; speedup 1.0000x reference)
//
#include <hip/hip_runtime.h>
#include <hip/hip_bf16.h>

#define N_NODES 1000000
#define D_IN 128
#define NG 4096
#define GSD 128
#define NPAD_MAX (N_NODES + NG * 31)   /* 1,126,976  (multiple of 32) */
#define NGROUP_MAX 35232               /* 8808 blocks * 4 waves >= 35218 */
#define K5_BLOCKS 8808

typedef __attribute__((ext_vector_type(4))) float f32x4;
typedef __attribute__((ext_vector_type(8))) short bf16x8;
typedef __attribute__((ext_vector_type(4))) int i32x4;

__device__ __forceinline__ short f2bs(float f) {
    unsigned u = __float_as_uint(f);
    u += 0x7FFF + ((u >> 16) & 1);   // round-to-nearest-even
    return (short)(u >> 16);
}

__device__ __forceinline__ float sigmoid_fast(float x) {
    float e = __builtin_amdgcn_exp2f(-1.44269504089f * x);
    return __builtin_amdgcn_rcpf(1.0f + e);
}

// ---------------- weight transpose + bf16 convert ----------------
// w1t[n*128+k] = bf16(W1[k][n]) (n<64,k<128);  w2t[n*64+k] = bf16(W2[k][n]) (n<256,k<64)
__global__ void wconv_kernel(const float* __restrict__ W1, const float* __restrict__ W2,
                             short* __restrict__ w1t, short* __restrict__ w2t) {
    int idx = blockIdx.x * 256 + threadIdx.x;
    if (idx < 8192) {
        int n = idx >> 7, k = idx & 127;
        w1t[idx] = f2bs(W1[k * 64 + n]);
    } else {
        int j = idx - 8192;
        int n = j >> 6, k = j & 63;
        w2t[j] = f2bs(W2[k * 256 + n]);
    }
}

// ---------------- histogram ----------------
__global__ void hist_kernel(const int* __restrict__ gidx, int* __restrict__ cnt) {
    __shared__ int h[NG];
    int t = threadIdx.x;
    for (int i = t; i < NG; i += 256) h[i] = 0;
    __syncthreads();
    for (int i = blockIdx.x * 256 + t; i < N_NODES; i += gridDim.x * 256)
        atomicAdd(&h[gidx[i]], 1);
    __syncthreads();
    for (int i = t; i < NG; i += 256) {
        int v = h[i];
        if (v) atomicAdd(&cnt[i], v);
    }
}

// ---------------- scan (padded offsets) + group-id fill ----------------
__global__ __launch_bounds__(1024) void scan_kernel(const int* __restrict__ cnt,
                                                    int* __restrict__ poff,
                                                    int* __restrict__ ggid) {
    __shared__ int sc[1024];
    int t = threadIdx.x;
    int c[4];
    int s = 0;
#pragma unroll
    for (int i = 0; i < 4; ++i) {
        int cc = cnt[t * 4 + i];
        c[i] = (cc + 31) & ~31;   // ceil to multiple of 32
        s += c[i];
    }
    sc[t] = s;
    __syncthreads();
    for (int off = 1; off < 1024; off <<= 1) {
        int v = (t >= off) ? sc[t - off] : 0;
        __syncthreads();
        sc[t] += v;
        __syncthreads();
    }
    int base = sc[t] - s;   // exclusive prefix (node units, multiple of 32)
#pragma unroll
    for (int i = 0; i < 4; ++i) {
        int g = t * 4 + i;
        poff[g] = base;
        int ngp = c[i] >> 5;
        int gb = base >> 5;
        for (int k = 0; k < ngp; ++k) ggid[gb + k] = g;
        base += c[i];
    }
}

// ---------------- scatter node ids into padded graph-sorted order ----------------
__global__ void scatter_kernel(const int* __restrict__ gidx, const int* __restrict__ poff,
                               int* __restrict__ cur, int* __restrict__ order) {
    int i = blockIdx.x * 256 + threadIdx.x;
    if (i >= N_NODES) return;
    int g = gidx[i];
    int p = atomicAdd(&cur[g], 1);
    order[poff[g] + p] = i;
}

// ---------------- main fused kernel: gather + MLP1 (MFMA bf16) + gate + reduce ----------------
// LDS layout (shorts): W1T [64 rows][stride 136] @0 (8704), W2T [256][stride 72] @8704 (18432),
// H1 per-wave [32][stride 72] @27136 (+wave*2304). Total 36352 shorts = 72,704 B.
__global__ __launch_bounds__(256, 2) void main_kernel(
        const float* __restrict__ X, const short* __restrict__ w1t,
        const short* __restrict__ w2t, const float* __restrict__ b1,
        const float* __restrict__ b2, const int* __restrict__ order,
        const int* __restrict__ ggid, float* __restrict__ gs) {
    __shared__ __align__(16) short lds[36352];
    const int tid = threadIdx.x;

    // stage W1T: 64 rows * 16 chunks of 8 shorts
    for (int ci = tid; ci < 1024; ci += 256) {
        int n = ci >> 4, cp = ci & 15;
        *(i32x4*)&lds[n * 136 + cp * 8] = *(const i32x4*)&w1t[n * 128 + cp * 8];
    }
    // stage W2T: 256 rows * 8 chunks
    for (int ci = tid; ci < 2048; ci += 256) {
        int n = ci >> 3, cp = ci & 7;
        *(i32x4*)&lds[8704 + n * 72 + cp * 8] = *(const i32x4*)&w2t[n * 64 + cp * 8];
    }
    __syncthreads();

    const int w = (blockIdx.x << 2) + (tid >> 6);   // global wave/group id
    const int lane = tid & 63;
    const int l15 = lane & 15;
    const int q = lane >> 4;
    const int h1base = 27136 + (tid >> 6) * 2304;
    const int g = ggid[w];
    const bool active = (g >= 0);
    unsigned rowmask = 0;

    if (active) {
        int nd0 = order[w * 32 + l15];
        int nd1 = order[w * 32 + 16 + l15];
        unsigned long long m0 = __ballot(nd0 >= 0);
        unsigned long long m1 = __ballot(nd1 >= 0);
        rowmask = ((unsigned)(m1 & 0xFFFFULL) << 16) | (unsigned)(m0 & 0xFFFFULL);
        bool v0 = nd0 >= 0, v1 = nd1 >= 0;
        const float* xp0 = X + (long long)(v0 ? nd0 : 0) * D_IN;
        const float* xp1 = X + (long long)(v1 ? nd1 : 0) * D_IN;

        f32x4 acc1[2][4];
#pragma unroll
        for (int mt = 0; mt < 2; ++mt)
#pragma unroll
            for (int nt = 0; nt < 4; ++nt) acc1[mt][nt] = (f32x4){0.f, 0.f, 0.f, 0.f};

        const f32x4 z = {0.f, 0.f, 0.f, 0.f};
#pragma unroll
        for (int kk = 0; kk < 4; ++kk) {
            int koff = kk * 32 + q * 8;
            f32x4 x00 = v0 ? *(const f32x4*)(xp0 + koff) : z;
            f32x4 x01 = v0 ? *(const f32x4*)(xp0 + koff + 4) : z;
            f32x4 x10 = v1 ? *(const f32x4*)(xp1 + koff) : z;
            f32x4 x11 = v1 ? *(const f32x4*)(xp1 + koff + 4) : z;
            bf16x8 a0, a1;
#pragma unroll
            for (int j = 0; j < 4; ++j) {
                a0[j] = f2bs(x00[j]); a0[4 + j] = f2bs(x01[j]);
                a1[j] = f2bs(x10[j]); a1[4 + j] = f2bs(x11[j]);
            }
#pragma unroll
            for (int nt = 0; nt < 4; ++nt) {
                bf16x8 b = *(const bf16x8*)&lds[(nt * 16 + l15) * 136 + koff];
                acc1[0][nt] = __builtin_amdgcn_mfma_f32_16x16x32_bf16(a0, b, acc1[0][nt], 0, 0, 0);
                acc1[1][nt] = __builtin_amdgcn_mfma_f32_16x16x32_bf16(a1, b, acc1[1][nt], 0, 0, 0);
            }
        }
        // epilogue 1: +b1, relu, bf16 -> H1 (A-operand layout round-trip)
#pragma unroll
        for (int nt = 0; nt < 4; ++nt) {
            float bb = b1[nt * 16 + l15];
#pragma unroll
            for (int mt = 0; mt < 2; ++mt)
#pragma unroll
                for (int r = 0; r < 4; ++r) {
                    float h = fmaxf(acc1[mt][nt][r] + bb, 0.f);
                    lds[h1base + (mt * 16 + q * 4 + r) * 72 + nt * 16 + l15] = f2bs(h);
                }
        }
    }
    __syncthreads();   // all waves reach (no early exit -> no barrier hang)
    if (active) {
        f32x4 acc2[2][16];
#pragma unroll
        for (int mt = 0; mt < 2; ++mt)
#pragma unroll
            for (int nt = 0; nt < 16; ++nt) acc2[mt][nt] = (f32x4){0.f, 0.f, 0.f, 0.f};

#pragma unroll
        for (int ks = 0; ks < 2; ++ks) {
            int koff = ks * 32 + q * 8;
            bf16x8 a0 = *(const bf16x8*)&lds[h1base + l15 * 72 + koff];
            bf16x8 a1 = *(const bf16x8*)&lds[h1base + (16 + l15) * 72 + koff];
#pragma unroll
            for (int nt = 0; nt < 16; ++nt) {
                bf16x8 b = *(const bf16x8*)&lds[8704 + (nt * 16 + l15) * 72 + koff];
                acc2[0][nt] = __builtin_amdgcn_mfma_f32_16x16x32_bf16(a0, b, acc2[0][nt], 0, 0, 0);
                acc2[1][nt] = __builtin_amdgcn_mfma_f32_16x16x32_bf16(a1, b, acc2[1][nt], 0, 0, 0);
            }
        }
        // epilogue 2: gate = sigmoid(h[:,:128]); gated = h[:,128:]*gate; masked 32-row reduce; atomic
#pragma unroll
        for (int nt = 0; nt < 8; ++nt) {
            float bg = b2[nt * 16 + l15];
            float bv = b2[128 + nt * 16 + l15];
            float s = 0.f;
#pragma unroll
            for (int mt = 0; mt < 2; ++mt)
#pragma unroll
                for (int r = 0; r < 4; ++r) {
                    int row = mt * 16 + q * 4 + r;
                    float gate = sigmoid_fast(acc2[mt][nt][r] + bg);
                    float val = acc2[mt][nt + 8][r] + bv;
                    float gv = gate * val;
                    s += ((rowmask >> row) & 1u) ? gv : 0.f;
                }
            s += __shfl_xor(s, 16);
            s += __shfl_xor(s, 32);
            if (lane < 16) unsafeAtomicAdd(&gs[(long long)g * GSD + nt * 16 + l15], s);
        }
    }
}

// ---------------- MLP2: [4096,128] -> relu(@W3+b3) -> @W4+b4 -> [4096,16] ----------------
__global__ void mlp2_kernel(const float* __restrict__ gs, const float* __restrict__ W3,
                            const float* __restrict__ b3, const float* __restrict__ W4,
                            const float* __restrict__ b4, float* __restrict__ out) {
    __shared__ __align__(16) float sgs[8 * 128];
    __shared__ float sh3[8 * 32];
    int t = threadIdx.x;
    int g0 = blockIdx.x * 8;
    *(f32x4*)&sgs[t * 4] = *(const f32x4*)(gs + (long long)g0 * 128 + t * 4);
    __syncthreads();
    {
        int li = t >> 5, j = t & 31;
        float acc = b3[j];
#pragma unroll 8
        for (int k = 0; k < 128; ++k) acc += sgs[li * 128 + k] * W3[k * 32 + j];
        sh3[li * 32 + j] = fmaxf(acc, 0.f);
    }
    __syncthreads();
    if (t < 128) {
        int li = t >> 4, o = t & 15;
        float acc = b4[o];
#pragma unroll
        for (int j = 0; j < 32; ++j) acc += sh3[li * 32 + j] * W4[j * 16 + o];
        out[(g0 + li) * 16 + o] = acc;
    }
}

extern "C" void kernel_launch(void* const* d_in, const int* in_sizes, int n_in,
                              void* d_out, int out_size, void* d_ws, size_t ws_size,
                              hipStream_t stream) {
    (void)in_sizes; (void)n_in; (void)out_size; (void)ws_size;
    const float* X  = (const float*)d_in[0];
    const int* gidx = (const int*)d_in[1];
    const float* W1 = (const float*)d_in[2];
    const float* b1 = (const float*)d_in[3];
    const float* W2 = (const float*)d_in[4];
    const float* b2 = (const float*)d_in[5];
    const float* W3 = (const float*)d_in[6];
    const float* b3 = (const float*)d_in[7];
    const float* W4 = (const float*)d_in[8];
    const float* b4 = (const float*)d_in[9];
    float* out = (float*)d_out;

    char* ws   = (char*)d_ws;
    float* gs  = (float*)(ws + 0);          // 2,097,152 B
    int* cnt   = (int*)(ws + 2097152);      // 16,384 B
    int* cur   = (int*)(ws + 2113536);      // 16,384 B
    int* poff  = (int*)(ws + 2129920);      // 16,384 B
    int* ggid  = (int*)(ws + 2146304);      // 140,928 B (35232 ints)
    short* w1t = (short*)(ws + 2287232);    // 16,384 B
    short* w2t = (short*)(ws + 2303616);    // 32,768 B
    int* order = (int*)(ws + 2336384);      // 4,507,904 B -> end 6,844,288 B

    hipMemsetAsync(ws, 0, 2146304, stream);               // gs + cnt + cur + poff
    hipMemsetAsync(ws + 2146304, 0xFF, 140928, stream);   // ggid = -1
    hipMemsetAsync(ws + 2336384, 0xFF, 4507904, stream);  // order = -1

    wconv_kernel<<<96, 256, 0, stream>>>(W1, W2, w1t, w2t);
    hist_kernel<<<512, 256, 0, stream>>>(gidx, cnt);
    scan_kernel<<<1, 1024, 0, stream>>>(cnt, poff, ggid);
    scatter_kernel<<<(N_NODES + 255) / 256, 256, 0, stream>>>(gidx, poff, cur, order);
    main_kernel<<<K5_BLOCKS, 256, 0, stream>>>(X, w1t, w2t, b1, b2, order, ggid, gs);
    mlp2_kernel<<<512, 256, 0, stream>>>(gs, W3, b3, W4, b4, out);
}

// Round 2
// 860.563 us; speedup vs baseline: 1.0478x; 1.0478x over previous
//
#include <hip/hip_runtime.h>
#include <hip/hip_bf16.h>

#define N_NODES 1000000
#define D_IN 128
#define NG 4096
#define GSD 128
#define NGROUP_MAX 35232               /* 8808 blocks * 4 waves >= 35218 worst case */
#define K5_BLOCKS 8808

typedef __attribute__((ext_vector_type(4))) float f32x4;
typedef __attribute__((ext_vector_type(8))) short bf16x8;
typedef __attribute__((ext_vector_type(4))) int i32x4;

__device__ __forceinline__ short f2bs(float f) {
    unsigned u = __float_as_uint(f);
    u += 0x7FFF + ((u >> 16) & 1);   // round-to-nearest-even
    return (short)(u >> 16);
}

__device__ __forceinline__ float sigmoid_fast(float x) {
    float e = __builtin_amdgcn_exp2f(-1.44269504089f * x);
    return __builtin_amdgcn_rcpf(1.0f + e);
}

// ---------------- weight transpose + bf16 convert (XOR-swizzled chunk layout) ----------------
// w1t slot n*128 + c*8 + j holds bf16(W1[k][n]) with k = ((c ^ (n&15))<<3)|j   (n<64, k<128)
// w2t slot n*64  + c*8 + j holds bf16(W2[k][n]) with k = ((c ^ (n&7 ))<<3)|j   (n<256, k<64)
__global__ void wconv_kernel(const float* __restrict__ W1, const float* __restrict__ W2,
                             short* __restrict__ w1t, short* __restrict__ w2t) {
    int idx = blockIdx.x * 256 + threadIdx.x;
    if (idx < 8192) {
        int n = idx >> 7, rem = idx & 127, c = rem >> 3, j = rem & 7;
        int k = ((c ^ (n & 15)) << 3) | j;
        w1t[idx] = f2bs(W1[k * 64 + n]);
    } else {
        int s = idx - 8192;
        int n = s >> 6, rem = s & 63, c = rem >> 3, j = rem & 7;
        int k = ((c ^ (n & 7)) << 3) | j;
        w2t[s] = f2bs(W2[k * 256 + n]);
    }
}

// ---------------- histogram ----------------
__global__ void hist_kernel(const int* __restrict__ gidx, int* __restrict__ cnt) {
    __shared__ int h[NG];
    int t = threadIdx.x;
    for (int i = t; i < NG; i += 256) h[i] = 0;
    __syncthreads();
    for (int i = blockIdx.x * 256 + t; i < N_NODES; i += gridDim.x * 256)
        atomicAdd(&h[gidx[i]], 1);
    __syncthreads();
    for (int i = t; i < NG; i += 256) {
        int v = h[i];
        if (v) atomicAdd(&cnt[i], v);
    }
}

// ---------------- scan (padded offsets) + encoded group-id fill + group count ----------------
__global__ __launch_bounds__(1024) void scan_kernel(const int* __restrict__ cnt,
                                                    int* __restrict__ poff,
                                                    int* __restrict__ ggid,
                                                    int* __restrict__ meta) {
    __shared__ int sc[1024];
    int t = threadIdx.x;
    int cc[4], c[4];
    int s = 0;
#pragma unroll
    for (int i = 0; i < 4; ++i) {
        cc[i] = cnt[t * 4 + i];
        c[i] = (cc[i] + 31) & ~31;   // ceil to multiple of 32
        s += c[i];
    }
    sc[t] = s;
    __syncthreads();
    for (int off = 1; off < 1024; off <<= 1) {
        int v = (t >= off) ? sc[t - off] : 0;
        __syncthreads();
        sc[t] += v;
        __syncthreads();
    }
    if (t == 1023) meta[0] = sc[1023] >> 5;   // total #32-row groups
    int base = sc[t] - s;   // exclusive prefix (node units, multiple of 32)
#pragma unroll
    for (int i = 0; i < 4; ++i) {
        int g = t * 4 + i;
        poff[g] = base;
        int ngp = c[i] >> 5;
        int gb = base >> 5;
        for (int k = 0; k < ngp; ++k) {
            int rem = cc[i] - k * 32;
            int rows = rem > 32 ? 32 : rem;
            ggid[gb + k] = (g << 6) | (rows - 1);
        }
        base += c[i];
    }
}

// ---------------- scatter node ids into padded graph-sorted order ----------------
__global__ void scatter_kernel(const int* __restrict__ gidx, const int* __restrict__ poff,
                               int* __restrict__ cur, int* __restrict__ order) {
    int i = blockIdx.x * 256 + threadIdx.x;
    if (i >= N_NODES) return;
    int g = gidx[i];
    int p = atomicAdd(&cur[g], 1);
    order[poff[g] + p] = i;
}

// ---------------- main fused kernel ----------------
// LDS (shorts): W2T [0,16384)  |  shared region [16384,24576): W1T (8192, layer1) then
// per-wave H1 (4 x 2048, layer2).  Total 24576 shorts = 49,152 B -> 3 blocks/CU.
__global__ __launch_bounds__(256, 3) void main_kernel(
        const float* __restrict__ X, const short* __restrict__ w1t,
        const short* __restrict__ w2t, const float* __restrict__ b1,
        const float* __restrict__ b2, const int* __restrict__ order,
        const int* __restrict__ ggid, const int* __restrict__ meta,
        float* __restrict__ gs) {
    __shared__ __align__(16) short lds[24576];
    const int tid = threadIdx.x;

    // stage W2T (16384 shorts) + W1T (8192 shorts) — pure linear 16 B copies
    for (int ci = tid; ci < 2048; ci += 256)
        *(i32x4*)&lds[ci * 8] = *(const i32x4*)&w2t[ci * 8];
    for (int ci = tid; ci < 1024; ci += 256)
        *(i32x4*)&lds[16384 + ci * 8] = *(const i32x4*)&w1t[ci * 8];

    const int wid = tid >> 6;
    const int w = (blockIdx.x << 2) + wid;   // global 32-row group id
    const int lane = tid & 63;
    const int l15 = lane & 15;
    const int q = lane >> 4;
    const int ngroups = meta[0];
    const bool active = (w < ngroups);

    int g = 0, rows = 0;
    unsigned rowmask = 0;
    f32x4 acc1[2][4];

    __syncthreads();   // weights staged

    if (active) {
        int enc = ggid[w];
        g = enc >> 6;
        rows = (enc & 63) + 1;
        rowmask = (rows >= 32) ? 0xFFFFFFFFu : ((1u << rows) - 1u);
        bool v0 = l15 < rows;
        bool v1 = (16 + l15) < rows;
        int nd0r = order[w * 32 + l15];
        int nd1r = order[w * 32 + 16 + l15];
        const float* xp0 = X + (long long)(v0 ? nd0r : 0) * D_IN;
        const float* xp1 = X + (long long)(v1 ? nd1r : 0) * D_IN;

#pragma unroll
        for (int mt = 0; mt < 2; ++mt)
#pragma unroll
            for (int nt = 0; nt < 4; ++nt) acc1[mt][nt] = (f32x4){0.f, 0.f, 0.f, 0.f};

        const f32x4 z = {0.f, 0.f, 0.f, 0.f};
#pragma unroll
        for (int kk = 0; kk < 4; ++kk) {
            int koff = kk * 32 + q * 8;
            f32x4 x00 = v0 ? *(const f32x4*)(xp0 + koff) : z;
            f32x4 x01 = v0 ? *(const f32x4*)(xp0 + koff + 4) : z;
            f32x4 x10 = v1 ? *(const f32x4*)(xp1 + koff) : z;
            f32x4 x11 = v1 ? *(const f32x4*)(xp1 + koff + 4) : z;
            bf16x8 a0, a1;
#pragma unroll
            for (int j = 0; j < 4; ++j) {
                a0[j] = f2bs(x00[j]); a0[4 + j] = f2bs(x01[j]);
                a1[j] = f2bs(x10[j]); a1[4 + j] = f2bs(x11[j]);
            }
            int ch = (kk * 4 + q);
#pragma unroll
            for (int nt = 0; nt < 4; ++nt) {
                bf16x8 b = *(const bf16x8*)&lds[16384 + (nt * 16 + l15) * 128 + ((ch ^ l15) << 3)];
                acc1[0][nt] = __builtin_amdgcn_mfma_f32_16x16x32_bf16(a0, b, acc1[0][nt], 0, 0, 0);
                acc1[1][nt] = __builtin_amdgcn_mfma_f32_16x16x32_bf16(a1, b, acc1[1][nt], 0, 0, 0);
            }
        }
    }

    __syncthreads();   // all layer-1 W1T reads done; region is reusable

    const int h1b = 16384 + wid * 2048;
    if (active) {
        // epilogue 1: +b1, relu, bf16 -> H1 (swizzled A-operand layout)
#pragma unroll
        for (int nt = 0; nt < 4; ++nt) {
            float bb = b1[nt * 16 + l15];
            int c = nt * 2 + (l15 >> 3);
            int j7 = l15 & 7;
#pragma unroll
            for (int mt = 0; mt < 2; ++mt)
#pragma unroll
                for (int r = 0; r < 4; ++r) {
                    int m = mt * 16 + q * 4 + r;
                    float h = fmaxf(acc1[mt][nt][r] + bb, 0.f);
                    lds[h1b + m * 64 + ((c ^ (m & 7)) << 3) + j7] = f2bs(h);
                }
        }
    }

    __syncthreads();   // H1 visible to the wave (and region consistent)

    if (active) {
        // hoist A fragments once: rows 0-15 and 16-31, K slices 0/1
        bf16x8 A0[2], A1[2];
#pragma unroll
        for (int ks = 0; ks < 2; ++ks) {
            int ch = ((ks * 4 + q) ^ (l15 & 7)) << 3;
            A0[ks] = *(const bf16x8*)&lds[h1b + l15 * 64 + ch];
            A1[ks] = *(const bf16x8*)&lds[h1b + (16 + l15) * 64 + ch];
        }
#pragma unroll
        for (int nt = 0; nt < 8; ++nt) {
            f32x4 aG0 = (f32x4){0.f, 0.f, 0.f, 0.f}, aG1 = aG0, aV0 = aG0, aV1 = aG0;
#pragma unroll
            for (int ks = 0; ks < 2; ++ks) {
                int ch = ((ks * 4 + q) ^ (l15 & 7)) << 3;
                bf16x8 bG = *(const bf16x8*)&lds[(nt * 16 + l15) * 64 + ch];
                bf16x8 bV = *(const bf16x8*)&lds[((nt + 8) * 16 + l15) * 64 + ch];
                aG0 = __builtin_amdgcn_mfma_f32_16x16x32_bf16(A0[ks], bG, aG0, 0, 0, 0);
                aG1 = __builtin_amdgcn_mfma_f32_16x16x32_bf16(A1[ks], bG, aG1, 0, 0, 0);
                aV0 = __builtin_amdgcn_mfma_f32_16x16x32_bf16(A0[ks], bV, aV0, 0, 0, 0);
                aV1 = __builtin_amdgcn_mfma_f32_16x16x32_bf16(A1[ks], bV, aV1, 0, 0, 0);
            }
            float bg = b2[nt * 16 + l15];
            float bv = b2[128 + nt * 16 + l15];
            float s = 0.f;
#pragma unroll
            for (int mt = 0; mt < 2; ++mt) {
                f32x4 aG = mt ? aG1 : aG0;
                f32x4 aV = mt ? aV1 : aV0;
#pragma unroll
                for (int r = 0; r < 4; ++r) {
                    int row = mt * 16 + q * 4 + r;
                    float gate = sigmoid_fast(aG[r] + bg);
                    float gv = gate * (aV[r] + bv);
                    s += ((rowmask >> row) & 1u) ? gv : 0.f;
                }
            }
            s += __shfl_xor(s, 16);
            s += __shfl_xor(s, 32);
            if (lane < 16) unsafeAtomicAdd(&gs[(long long)g * GSD + nt * 16 + l15], s);
        }
    }
}

// ---------------- MLP2: [4096,128] -> relu(@W3+b3) -> @W4+b4 -> [4096,16] ----------------
__global__ void mlp2_kernel(const float* __restrict__ gs, const float* __restrict__ W3,
                            const float* __restrict__ b3, const float* __restrict__ W4,
                            const float* __restrict__ b4, float* __restrict__ out) {
    __shared__ __align__(16) float sgs[8 * 128];
    __shared__ float sh3[8 * 32];
    int t = threadIdx.x;
    int g0 = blockIdx.x * 8;
    *(f32x4*)&sgs[t * 4] = *(const f32x4*)(gs + (long long)g0 * 128 + t * 4);
    __syncthreads();
    {
        int li = t >> 5, j = t & 31;
        float acc = b3[j];
#pragma unroll 8
        for (int k = 0; k < 128; ++k) acc += sgs[li * 128 + k] * W3[k * 32 + j];
        sh3[li * 32 + j] = fmaxf(acc, 0.f);
    }
    __syncthreads();
    if (t < 128) {
        int li = t >> 4, o = t & 15;
        float acc = b4[o];
#pragma unroll
        for (int j = 0; j < 32; ++j) acc += sh3[li * 32 + j] * W4[j * 16 + o];
        out[(g0 + li) * 16 + o] = acc;
    }
}

extern "C" void kernel_launch(void* const* d_in, const int* in_sizes, int n_in,
                              void* d_out, int out_size, void* d_ws, size_t ws_size,
                              hipStream_t stream) {
    (void)in_sizes; (void)n_in; (void)out_size; (void)ws_size;
    const float* X  = (const float*)d_in[0];
    const int* gidx = (const int*)d_in[1];
    const float* W1 = (const float*)d_in[2];
    const float* b1 = (const float*)d_in[3];
    const float* W2 = (const float*)d_in[4];
    const float* b2 = (const float*)d_in[5];
    const float* W3 = (const float*)d_in[6];
    const float* b3 = (const float*)d_in[7];
    const float* W4 = (const float*)d_in[8];
    const float* b4 = (const float*)d_in[9];
    float* out = (float*)d_out;

    char* ws   = (char*)d_ws;
    float* gs  = (float*)(ws + 0);          // 2,097,152 B
    int* cnt   = (int*)(ws + 2097152);      // 16,384 B
    int* cur   = (int*)(ws + 2113536);      // 16,384 B
    int* poff  = (int*)(ws + 2129920);      // 16,384 B
    int* meta  = (int*)(ws + 2146304);      // 64 B
    short* w1t = (short*)(ws + 2146368);    // 16,384 B
    short* w2t = (short*)(ws + 2162752);    // 32,768 B
    int* ggid  = (int*)(ws + 2195520);      // 140,928 B
    int* order = (int*)(ws + 2336448);      // 4,507,904 B -> end 6,844,352 B

    // zero gs + cnt + cur in one fill (poff/meta/ggid/order are fully written before use)
    hipMemsetAsync(ws, 0, 2129920, stream);

    wconv_kernel<<<96, 256, 0, stream>>>(W1, W2, w1t, w2t);
    hist_kernel<<<512, 256, 0, stream>>>(gidx, cnt);
    scan_kernel<<<1, 1024, 0, stream>>>(cnt, poff, ggid, meta);
    scatter_kernel<<<(N_NODES + 255) / 256, 256, 0, stream>>>(gidx, poff, cur, order);
    main_kernel<<<K5_BLOCKS, 256, 0, stream>>>(X, w1t, w2t, b1, b2, order, ggid, meta, gs);
    mlp2_kernel<<<512, 256, 0, stream>>>(gs, W3, b3, W4, b4, out);
}